// Round 1
// baseline (142.558 us; speedup 1.0000x reference)
//
#include <hip/hip_runtime.h>
#include <hip/hip_bf16.h>

#define NTHREADS 256
#define N_RBF 16
#define HIDDEN 64

// One block per atom (B*N blocks). 256 threads:
//  - phase 1: strided loop over all N neighbors, accumulate 32 env features
//    (16 RBF x 2 species) in registers, butterfly-reduce per wave, combine
//    4 waves via LDS.
//  - phase 2: wave 0 (64 threads) runs the 34->64->64->64 SiLU MLP, one
//    output unit per thread, reading feats/hidden from LDS. Weight reads are
//    coalesced (row k, 64 consecutive floats).
__global__ __launch_bounds__(NTHREADS) void LocalFeatureEncoder_40063454937486_kernel(
    const float* __restrict__ pos,    // [B,N,3]
    const int*   __restrict__ types,  // [B,N]
    const float* __restrict__ W1,     // [34,64]
    const float* __restrict__ b1,     // [64]
    const float* __restrict__ W2,     // [64,64]
    const float* __restrict__ b2,     // [64]
    const float* __restrict__ W3,     // [64,64]
    const float* __restrict__ b3,     // [64]
    float*       __restrict__ out,    // [B,N,64]
    int N)
{
    const int a    = blockIdx.x;      // global atom index b*N + i
    const int bidx = a / N;
    const int i    = a - bidx * N;
    const int tid  = threadIdx.x;

    __shared__ float feats[64];        // 34 used for layer-1 input; reused as h2
    __shared__ float h1s[64];
    __shared__ float partial[4 * 32];  // per-wave env partials

    const float* posb = pos + (size_t)bidx * N * 3;
    const int*   typb = types + (size_t)bidx * N;

    const float xi = posb[i * 3 + 0];
    const float yi = posb[i * 3 + 1];
    const float zi = posb[i * 3 + 2];

    constexpr float CUT   = 2.5f;
    constexpr float STEP  = 2.5f / 15.0f;                  // RBF center spacing = width
    const float inv_w2    = 1.0f / (STEP * STEP + 1e-12f);
    const float inv_cut   = 1.0f / CUT;

    float acc[32];
#pragma unroll
    for (int k = 0; k < 32; k++) acc[k] = 0.0f;

    for (int j = tid; j < N; j += NTHREADS) {
        const float dx = xi - posb[j * 3 + 0];
        const float dy = yi - posb[j * 3 + 1];
        const float dz = zi - posb[j * 3 + 2];
        const float sq = dx * dx + dy * dy + dz * dz;
        if (j != i && sq < CUT * CUT) {
            const float d  = sqrtf(sq);
            const float x  = d * inv_cut;
            const float x3 = x * x * x;
            // 1 - 6x^5 + 15x^4 - 10x^3
            const float cutv = 1.0f + x3 * (-10.0f + x * (15.0f - 6.0f * x));
            const int   tj = typb[j];
            const float m0 = (tj == 0) ? cutv : 0.0f;
            const float m1 = (tj == 0) ? 0.0f : cutv;
#pragma unroll
            for (int r = 0; r < N_RBF; r++) {
                const float diff = d - (float)r * STEP;
                const float e = __expf(-(diff * diff) * inv_w2);
                acc[r * 2 + 0] += e * m0;   // env layout: [r][s], s fastest
                acc[r * 2 + 1] += e * m1;
            }
        }
    }

    // butterfly reduce across the 64-lane wave
#pragma unroll
    for (int k = 0; k < 32; k++) {
        float v = acc[k];
#pragma unroll
        for (int m = 1; m < 64; m <<= 1) v += __shfl_xor(v, m, 64);
        acc[k] = v;
    }
    const int wave = tid >> 6;
    const int lane = tid & 63;
    if (lane == 0) {
#pragma unroll
        for (int k = 0; k < 32; k++) partial[wave * 32 + k] = acc[k];
    }
    __syncthreads();

    if (tid < 32) {
        feats[2 + tid] = partial[tid] + partial[32 + tid] + partial[64 + tid] + partial[96 + tid];
    }
    if (tid == 0) {
        const int ti = typb[i];
        feats[0] = (ti == 0) ? 1.0f : 0.0f;
        feats[1] = (ti == 1) ? 1.0f : 0.0f;
    }
    __syncthreads();

    // layer 1: 34 -> 64, SiLU
    if (tid < HIDDEN) {
        float h = b1[tid];
#pragma unroll
        for (int k = 0; k < 34; k++) h += feats[k] * W1[k * HIDDEN + tid];
        h = h / (1.0f + __expf(-h));
        h1s[tid] = h;
    }
    __syncthreads();

    // layer 2: 64 -> 64, SiLU (write into feats, reads only h1s)
    if (tid < HIDDEN) {
        float h = b2[tid];
#pragma unroll
        for (int k = 0; k < HIDDEN; k++) h += h1s[k] * W2[k * HIDDEN + tid];
        h = h / (1.0f + __expf(-h));
        feats[tid] = h;
    }
    __syncthreads();

    // layer 3: 64 -> 64, linear
    if (tid < HIDDEN) {
        float o = b3[tid];
#pragma unroll
        for (int k = 0; k < HIDDEN; k++) o += feats[k] * W3[k * HIDDEN + tid];
        out[(size_t)a * HIDDEN + tid] = o;
    }
}

extern "C" void kernel_launch(void* const* d_in, const int* in_sizes, int n_in,
                              void* d_out, int out_size, void* d_ws, size_t ws_size,
                              hipStream_t stream) {
    const float* pos   = (const float*)d_in[0];
    const int*   types = (const int*)d_in[1];
    const float* W1    = (const float*)d_in[2];
    const float* b1    = (const float*)d_in[3];
    const float* W2    = (const float*)d_in[4];
    const float* b2    = (const float*)d_in[5];
    const float* W3    = (const float*)d_in[6];
    const float* b3    = (const float*)d_in[7];
    float*       out   = (float*)d_out;

    const int N  = 1024;               // fixed by setup_inputs()
    const int BN = in_sizes[1];        // B*N = 8192

    LocalFeatureEncoder_40063454937486_kernel<<<BN, NTHREADS, 0, stream>>>(
        pos, types, W1, b1, W2, b2, W3, b3, out, N);
}

// Round 2
// 91.677 us; speedup vs baseline: 1.5550x; 1.5550x over previous
//
#include <hip/hip_runtime.h>
#include <hip/hip_bf16.h>

#define NTHREADS 256
#define N_ATOMS 1024
#define HIDDEN 64

// One block per atom (B*N = 8192 blocks), 256 threads.
// Phase 1a: 4 strided sweeps over the 1024 neighbors; compute squared
//   distance; ballot-compact survivors (d, cutv masked by species) into an
//   LDS queue (~65 entries expected, 1024 worst case).
// Phase 1b: thread = (pair-slot p = tid>>5, feature f = tid&31).  Each
//   thread accumulates ONE of the 32 env features over queue entries
//   e = p, p+8, ...  -> dense exp work, trivial reduction (shfl_xor(32)
//   + 4-wave LDS combine).
// Phase 2: threads 0..63 run the 34->64->64->64 SiLU MLP from LDS;
//   weight reads coalesced (row k = 64 consecutive floats, L1-resident).
__global__ __launch_bounds__(NTHREADS) void LocalFeatureEncoder_40063454937486_kernel(
    const float* __restrict__ pos,    // [B,N,3]
    const int*   __restrict__ types,  // [B,N]
    const float* __restrict__ W1,     // [34,64]
    const float* __restrict__ b1,     // [64]
    const float* __restrict__ W2,     // [64,64]
    const float* __restrict__ b2,     // [64]
    const float* __restrict__ W3,     // [64,64]
    const float* __restrict__ b3,     // [64]
    float*       __restrict__ out)    // [B,N,64]
{
    const int a    = blockIdx.x;          // b*N + i
    const int bidx = a >> 10;             // N = 1024
    const int i    = a & (N_ATOMS - 1);
    const int tid  = threadIdx.x;
    const int lane = tid & 63;
    const int wav  = tid >> 6;

    __shared__ float qd [N_ATOMS];        // queue: distance
    __shared__ float qm0[N_ATOMS];        // queue: cutv * (type==0)
    __shared__ float qm1[N_ATOMS];        // queue: cutv * (type==1)
    __shared__ float partial[4 * 32];
    __shared__ float feats[64];           // 34 used; reused as h2
    __shared__ float h1s[64];
    __shared__ int   cnt;

    if (tid == 0) cnt = 0;

    const float* posb = pos + (size_t)bidx * N_ATOMS * 3;
    const int*   typb = types + (size_t)bidx * N_ATOMS;

    const float xi = posb[i * 3 + 0];
    const float yi = posb[i * 3 + 1];
    const float zi = posb[i * 3 + 2];

    __syncthreads();                      // cnt = 0 visible

    // ---------- phase 1a: distances + stream compaction ----------
#pragma unroll
    for (int it = 0; it < N_ATOMS / NTHREADS; ++it) {
        const int j = tid + it * NTHREADS;
        const float px = posb[j * 3 + 0];
        const float py = posb[j * 3 + 1];
        const float pz = posb[j * 3 + 2];
        const int   tj = typb[j];
        const float dx = xi - px, dy = yi - py, dz = zi - pz;
        const float sq = dx * dx + dy * dy + dz * dz;
        const bool pred = (j != i) && (sq < 6.25f);

        const unsigned long long mask = __ballot(pred);
        int base = 0;
        if (lane == 0 && mask) base = atomicAdd(&cnt, (int)__popcll(mask));
        base = __shfl(base, 0, 64);       // convergent broadcast
        if (pred) {
            const float d  = sqrtf(sq);
            const float x  = d * 0.4f;    // d / 2.5
            const float x3 = x * x * x;
            const float cutv = 1.0f + x3 * (-10.0f + x * (15.0f - 6.0f * x));
            const int idx = base + (int)__popcll(mask & ((1ull << lane) - 1ull));
            qd [idx] = d;
            qm0[idx] = (tj == 0) ? cutv : 0.0f;
            qm1[idx] = (tj == 0) ? 0.0f : cutv;
        }
    }
    __syncthreads();
    const int n = cnt;

    // ---------- phase 1b: feature-parallel RBF accumulation ----------
    const int p = tid >> 5;               // pair slot 0..7
    const int f = tid & 31;               // feature  0..31 (= r*2 + s)
    const int r = f >> 1;
    const int s = f & 1;
    const float c = (float)r * (2.5f / 15.0f);
    const float inv_w2 = 36.0f;           // 1/((2.5/15)^2 + 1e-12)
    const float* __restrict__ qm = (s == 0) ? qm0 : qm1;

    float acc = 0.0f;
    for (int e = p; e < n; e += 8) {
        const float d    = qd[e];
        const float m    = qm[e];
        const float diff = d - c;
        acc += m * __expf(-(diff * diff) * inv_w2);
    }
    acc += __shfl_xor(acc, 32, 64);       // combine the 2 pair-slots per wave
    if (lane < 32) partial[wav * 32 + f] = acc;
    if (tid == 0) {
        const int ti = typb[i];
        feats[0] = (ti == 0) ? 1.0f : 0.0f;
        feats[1] = (ti == 1) ? 1.0f : 0.0f;
    }
    __syncthreads();
    if (tid < 32)
        feats[2 + tid] = partial[tid] + partial[32 + tid] + partial[64 + tid] + partial[96 + tid];
    __syncthreads();

    // ---------- phase 2: MLP (threads 0..63) ----------
    if (tid < HIDDEN) {
        float h = b1[tid];
#pragma unroll
        for (int k = 0; k < 34; k++) h += feats[k] * W1[k * HIDDEN + tid];
        h = h / (1.0f + __expf(-h));
        h1s[tid] = h;
    }
    __syncthreads();
    if (tid < HIDDEN) {
        float h = b2[tid];
#pragma unroll
        for (int k = 0; k < HIDDEN; k++) h += h1s[k] * W2[k * HIDDEN + tid];
        h = h / (1.0f + __expf(-h));
        feats[tid] = h;
    }
    __syncthreads();
    if (tid < HIDDEN) {
        float o = b3[tid];
#pragma unroll
        for (int k = 0; k < HIDDEN; k++) o += feats[k] * W3[k * HIDDEN + tid];
        out[(size_t)a * HIDDEN + tid] = o;
    }
}

extern "C" void kernel_launch(void* const* d_in, const int* in_sizes, int n_in,
                              void* d_out, int out_size, void* d_ws, size_t ws_size,
                              hipStream_t stream) {
    const float* pos   = (const float*)d_in[0];
    const int*   types = (const int*)d_in[1];
    const float* W1    = (const float*)d_in[2];
    const float* b1    = (const float*)d_in[3];
    const float* W2    = (const float*)d_in[4];
    const float* b2    = (const float*)d_in[5];
    const float* W3    = (const float*)d_in[6];
    const float* b3    = (const float*)d_in[7];
    float*       out   = (float*)d_out;

    const int BN = in_sizes[1];           // B*N = 8192

    LocalFeatureEncoder_40063454937486_kernel<<<BN, NTHREADS, 0, stream>>>(
        pos, types, W1, b1, W2, b2, W3, b3, out);
}